// Round 8
// baseline (348.549 us; speedup 1.0000x reference)
//
#include <hip/hip_runtime.h>

// Problem constants
#define T_LEN 4096
#define DMODEL 512
#define DIM 512
#define NBATCH 8
#define MROWS (NBATCH * T_LEN)   // 32768
#define NCHUNK 128
#define LCHUNK 32                 // T_LEN / NCHUNK

typedef __attribute__((ext_vector_type(8))) short short8;
typedef __attribute__((ext_vector_type(4))) float float4v;

__device__ __forceinline__ ushort f2b(float f) {
    union { float fl; unsigned u; } v; v.fl = f;
    unsigned u = v.u;
    return (ushort)((u + 0x7FFFu + ((u >> 16) & 1u)) >> 16);
}
__device__ __forceinline__ float b2f(ushort u) {
    union { unsigned u; float f; } v; v.u = (unsigned)u << 16; return v.f;
}

__device__ __forceinline__ void glds16(const ushort* g, ushort* l) {
    __builtin_amdgcn_global_load_lds(
        (const __attribute__((address_space(1))) void*)g,
        (__attribute__((address_space(3))) void*)l, 16, 0, 0);
}

// ---------------- merged prep kernel (R6, verified) ----------------
#define XBLK (MROWS * 512 / 4 / 256)        // 16384
#define TBLK 256                            // 4 mats x 64 tiles of 64x64

__global__ __launch_bounds__(256) void k_prep(const float* __restrict__ x,
                                              const float* __restrict__ B_re,
                                              const float* __restrict__ B_im,
                                              const float* __restrict__ gamma_log,
                                              const float* __restrict__ C_re,
                                              const float* __restrict__ C_im,
                                              ushort* __restrict__ Xb,
                                              ushort* __restrict__ BT,
                                              ushort* __restrict__ CT) {
    __shared__ float T[64][65];
    int bb = blockIdx.x;
    if (bb < XBLK) {
        int i = (bb * 256 + threadIdx.x) * 4;
        float4 v = *(const float4*)(x + i);
        ushort4 o;
        o.x = f2b(v.x); o.y = f2b(v.y); o.z = f2b(v.z); o.w = f2b(v.w);
        *(ushort4*)(Xb + i) = o;
        return;
    }
    int tb = bb - XBLK;                 // 0..255
    int mat = tb >> 6;                  // 0=B_re 1=B_im 2=C_re 3=C_im
    int tile = tb & 63;
    int r0 = (tile >> 3) * 64;
    int c0 = (tile & 7) * 64;
    const float* IN = (mat == 0) ? B_re : (mat == 1) ? B_im : (mat == 2) ? C_re : C_im;
    int lr_ = threadIdx.x & 63;
    int lc  = threadIdx.x >> 6;
#pragma unroll
    for (int p = 0; p < 16; p++)
        T[4 * p + lc][lr_] = IN[(size_t)(c0 + 4 * p + lc) * 512 + r0 + lr_];
    __syncthreads();
#pragma unroll
    for (int p = 0; p < 16; p++) {
        int rr = 4 * p + lc;
        int r = r0 + rr;
        float v = T[lr_][rr];
        if (mat <= 1) {
            v *= __expf(gamma_log[r]);
            BT[(size_t)(mat * 512 + r) * 512 + c0 + lr_] = f2b(v);
        } else {
            if (mat == 3) v = -v;
            CT[(size_t)r * 1024 + (mat - 2) * 512 + c0 + lr_] = f2b(v);
        }
    }
}

// ---------------- bf16 MFMA GEMM: R1 structure + B-direct-from-L2 ----------------
// Feed-bound model (R7 analysis): R1 staged (BM+BN)*K*2 per block = 512 MB/GEMM at
// 7.9 TB/s glds feed = the measured 65-70 us. B (BT/CT) is only 1 MB and L2-resident,
// yet half the staged bytes were re-staging it per m-block. Fix: B fragments load
// DIRECT global->register (64 lanes cover 16 rows x 64 contiguous B, all L2 hits);
// A keeps the verified glds16 + XOR-swizzle path (0 bank conflicts). LDS 16 KB/block
// -> 3-4 blocks/CU preserved for cross-block feed overlap (m114). Staged bytes halve.
template<int K, int MODE, int NBN>
__global__ __launch_bounds__(256) void k_gemm(
    const ushort* __restrict__ A, const ushort* __restrict__ Bt,
    ushort* __restrict__ oRe, ushort* __restrict__ oIm,
    float* __restrict__ y, const float* __restrict__ x, const float* __restrict__ Dp) {
    __shared__ ushort sA[128 * 64];
    const int tid = threadIdx.x;
    // XCD-aware remap: round-robin block->XCD (L%8); XCD owns 32 m-blocks, n fastest.
    const int L = blockIdx.x;
    const int xcd = L & 7;
    const int slot = L >> 3;
    const int m0 = (xcd * 32 + slot / NBN) * 128;
    const int n0 = (slot % NBN) * 128;
    const int wave = tid >> 6;
    const int lane = tid & 63;
    const int wm = (wave >> 1) * 64;
    const int wn = (wave & 1) * 64;
    const int lr = lane & 15;
    const int quad = lane >> 4;

    // A staging: wave w covers rows [w*32, w*32+32), 4 calls x 8 rows.
    const int srow = lane >> 3;                 // 0..7 within 8-row group
    const int schunk = (lane & 7) ^ srow;       // XOR swizzle key = row&7 = srow
    const ushort* gA0 = A + (size_t)(m0 + wave * 32 + srow) * K + schunk * 8;
    // B direct: lane (lr, quad) covers row n0+wn+j*16+lr, k-chunk quad (16B); the 4
    // quads of one lr form 64 contiguous bytes of that row.
    const ushort* gB = Bt + (size_t)(n0 + wn + lr) * K + quad * 8;

    float4v acc[4][4];
#pragma unroll
    for (int i = 0; i < 4; i++)
#pragma unroll
        for (int j = 0; j < 4; j++) {
            float4v z = {0.f, 0.f, 0.f, 0.f};
            acc[i][j] = z;
        }

    for (int k0 = 0; k0 < K; k0 += 64) {
        // B fragments for this K-step: global->reg, independent of LDS/barriers,
        // issued before the staging sync so they overlap the A stage.
        short8 bfr[2][4];
#pragma unroll
        for (int kk = 0; kk < 2; kk++)
#pragma unroll
            for (int j = 0; j < 4; j++)
                bfr[kk][j] = *(const short8*)&gB[(size_t)(j * 16) * K + k0 + kk * 32];

        __syncthreads();   // all waves done reading sA of previous step
#pragma unroll
        for (int c = 0; c < 4; c++)
            glds16(gA0 + (size_t)(c * 8) * K + k0, &sA[(wave * 32 + c * 8) * 64]);
        __syncthreads();   // A staged (implicit vmcnt drain)

#pragma unroll
        for (int kk = 0; kk < 2; kk++) {
            short8 af[4];
#pragma unroll
            for (int i = 0; i < 4; i++) {
                int row = wm + i * 16 + lr;
                af[i] = *(const short8*)&sA[row * 64 + (((kk * 4 + quad) ^ (row & 7)) * 8)];
            }
#pragma unroll
            for (int i = 0; i < 4; i++)
#pragma unroll
                for (int j = 0; j < 4; j++)
                    acc[i][j] = __builtin_amdgcn_mfma_f32_16x16x32_bf16(af[i], bfr[kk][j], acc[i][j], 0, 0, 0);
        }
    }

    // epilogue: D[row][col], col = lane&15, row = quad*4 + r
#pragma unroll
    for (int i = 0; i < 4; i++) {
#pragma unroll
        for (int j = 0; j < 4; j++) {
            int gmb = m0 + wm + i * 16 + quad * 4;
            int gn = n0 + wn + j * 16 + lr;
#pragma unroll
            for (int r = 0; r < 4; r++) {
                float v = acc[i][j][r];
                int row = gmb + r;
                if (MODE == 1) {
                    if (gn < 512) oRe[(size_t)row * 512 + gn] = f2b(v);
                    else oIm[(size_t)row * 512 + (gn - 512)] = f2b(v);
                } else {
                    size_t o = (size_t)row * 512 + gn;
                    y[o] = v + Dp[gn] * x[o];
                }
            }
        }
    }
}

// ---------------- scan kernels (R6, verified) ----------------

__device__ __forceinline__ void lambda_of(const float* nu_log, const float* theta_log,
                                          int n, float& lre, float& lim) {
    float e = __expf(nu_log[n]);
    float th = __expf(theta_log[n]);
    float rad = __expf(-e);
    float s, c;
    __sincosf(th, &s, &c);
    lre = rad * c;
    lim = rad * s;
}

__global__ __launch_bounds__(256) void k_scan1(const ushort* __restrict__ BuRe,
                                               const ushort* __restrict__ BuIm,
                                               const float* __restrict__ nu_log,
                                               const float* __restrict__ theta_log,
                                               float* __restrict__ cRe, float* __restrict__ cIm) {
    int n2 = threadIdx.x;
    int b = blockIdx.x >> 7;
    int c = blockIdx.x & 127;
    float lre0, lim0, lre1, lim1;
    lambda_of(nu_log, theta_log, 2 * n2, lre0, lim0);
    lambda_of(nu_log, theta_log, 2 * n2 + 1, lre1, lim1);
    float hr0 = 0.f, hi0 = 0.f, hr1 = 0.f, hi1 = 0.f;
    size_t base = ((size_t)b * T_LEN + (size_t)c * LCHUNK) * 512 + 2 * n2;
#pragma unroll 8
    for (int j = 0; j < LCHUNK; j++) {
        ushort2 ur = *(const ushort2*)(BuRe + base + (size_t)j * 512);
        ushort2 ui = *(const ushort2*)(BuIm + base + (size_t)j * 512);
        float br0 = b2f(ur.x), br1 = b2f(ur.y), bi0 = b2f(ui.x), bi1 = b2f(ui.y);
        float nr0 = lre0 * hr0 - lim0 * hi0 + br0;
        float ni0 = lre0 * hi0 + lim0 * hr0 + bi0;
        hr0 = nr0; hi0 = ni0;
        float nr1 = lre1 * hr1 - lim1 * hi1 + br1;
        float ni1 = lre1 * hi1 + lim1 * hr1 + bi1;
        hr1 = nr1; hi1 = ni1;
    }
    size_t co = ((size_t)b * NCHUNK + c) * 512 + 2 * n2;
    *(float2*)(cRe + co) = make_float2(hr0, hr1);
    *(float2*)(cIm + co) = make_float2(hi0, hi1);
}

__global__ __launch_bounds__(256) void k_scanB(const ushort* __restrict__ BuRe,
                                               const ushort* __restrict__ BuIm,
                                               const float* __restrict__ cRe,
                                               const float* __restrict__ cIm,
                                               const float* __restrict__ h0,
                                               const float* __restrict__ nu_log,
                                               const float* __restrict__ theta_log,
                                               ushort* __restrict__ Hbf,
                                               float* __restrict__ newH, int newh_mode) {
    int n2 = threadIdx.x;
    int b = blockIdx.x >> 7;
    int c = blockIdx.x & 127;
    float lre0, lim0, lre1, lim1;
    lambda_of(nu_log, theta_log, 2 * n2, lre0, lim0);
    lambda_of(nu_log, theta_log, 2 * n2 + 1, lre1, lim1);
    float Lr0 = lre0, Li0 = lim0, Lr1 = lre1, Li1 = lim1;
#pragma unroll
    for (int s = 0; s < 5; s++) {
        float a0 = Lr0 * Lr0 - Li0 * Li0, q0 = 2.f * Lr0 * Li0; Lr0 = a0; Li0 = q0;
        float a1 = Lr1 * Lr1 - Li1 * Li1, q1 = 2.f * Lr1 * Li1; Lr1 = a1; Li1 = q1;
    }
    float fr0 = h0[b * 512 + 2 * n2], fi0 = 0.f;
    float fr1 = h0[b * 512 + 2 * n2 + 1], fi1 = 0.f;
    size_t cb = (size_t)b * NCHUNK * 512 + 2 * n2;
#pragma unroll 4
    for (int j = 0; j < c; j++) {
        float2 ar = *(const float2*)(cRe + cb + (size_t)j * 512);
        float2 ai = *(const float2*)(cIm + cb + (size_t)j * 512);
        float nr0 = Lr0 * fr0 - Li0 * fi0 + ar.x;
        float ni0 = Lr0 * fi0 + Li0 * fr0 + ai.x;
        fr0 = nr0; fi0 = ni0;
        float nr1 = Lr1 * fr1 - Li1 * fi1 + ar.y;
        float ni1 = Lr1 * fi1 + Li1 * fr1 + ai.y;
        fr1 = nr1; fi1 = ni1;
    }
    if (c == NCHUNK - 1) {
        float2 ar = *(const float2*)(cRe + cb + (size_t)(NCHUNK - 1) * 512);
        float2 ai = *(const float2*)(cIm + cb + (size_t)(NCHUNK - 1) * 512);
        float cr0 = Lr0 * fr0 - Li0 * fi0 + ar.x;
        float ci0 = Lr0 * fi0 + Li0 * fr0 + ai.x;
        float cr1 = Lr1 * fr1 - Li1 * fi1 + ar.y;
        float ci1 = Lr1 * fi1 + Li1 * fr1 + ai.y;
        size_t i0 = (size_t)b * 512 + 2 * n2;
        if (newh_mode == 1) {
            newH[i0] = cr0; newH[i0 + 1] = cr1;
            newH[(size_t)NBATCH * 512 + i0] = ci0;
            newH[(size_t)NBATCH * 512 + i0 + 1] = ci1;
        } else if (newh_mode == 2) {
            newH[i0] = cr0; newH[i0 + 1] = cr1;
        } else {
            newH[i0 * 2] = cr0; newH[i0 * 2 + 1] = ci0;
            newH[(i0 + 1) * 2] = cr1; newH[(i0 + 1) * 2 + 1] = ci1;
        }
    }
    float pr0 = lre0, pi0 = lim0, pr1 = lre1, pi1 = lim1;
    float hr0 = 0.f, hi0 = 0.f, hr1 = 0.f, hi1 = 0.f;
    size_t row0 = (size_t)b * T_LEN + (size_t)c * LCHUNK;
#pragma unroll 4
    for (int j = 0; j < LCHUNK; j++) {
        size_t base = (row0 + j) * 512 + 2 * n2;
        ushort2 ur = *(const ushort2*)(BuRe + base);
        ushort2 ui = *(const ushort2*)(BuIm + base);
        float br0 = b2f(ur.x), br1 = b2f(ur.y), bi0 = b2f(ui.x), bi1 = b2f(ui.y);
        float nr0 = lre0 * hr0 - lim0 * hi0 + br0;
        float ni0 = lre0 * hi0 + lim0 * hr0 + bi0;
        hr0 = nr0; hi0 = ni0;
        float nr1 = lre1 * hr1 - lim1 * hi1 + br1;
        float ni1 = lre1 * hi1 + lim1 * hr1 + bi1;
        hr1 = nr1; hi1 = ni1;
        float vr0 = hr0 + pr0 * fr0 - pi0 * fi0;
        float vi0 = hi0 + pr0 * fi0 + pi0 * fr0;
        float vr1 = hr1 + pr1 * fr1 - pi1 * fi1;
        float vi1 = hi1 + pr1 * fi1 + pi1 * fr1;
        size_t hrow = (row0 + j) * 1024;
        ushort2 wre, wim;
        wre.x = f2b(vr0); wre.y = f2b(vr1);
        wim.x = f2b(vi0); wim.y = f2b(vi1);
        *(ushort2*)(Hbf + hrow + 2 * n2) = wre;
        *(ushort2*)(Hbf + hrow + 512 + 2 * n2) = wim;
        float npr0 = pr0 * lre0 - pi0 * lim0;
        float npi0 = pr0 * lim0 + pi0 * lre0;
        pr0 = npr0; pi0 = npi0;
        float npr1 = pr1 * lre1 - pi1 * lim1;
        float npi1 = pr1 * lim1 + pi1 * lre1;
        pr1 = npr1; pi1 = npi1;
    }
}

// ---------------- launch ----------------

extern "C" void kernel_launch(void* const* d_in, const int* in_sizes, int n_in,
                              void* d_out, int out_size, void* d_ws, size_t ws_size,
                              hipStream_t stream) {
    const float* x         = (const float*)d_in[0];
    const float* h0        = (const float*)d_in[1];
    const float* nu_log    = (const float*)d_in[2];
    const float* theta_log = (const float*)d_in[3];
    const float* B_re      = (const float*)d_in[4];
    const float* B_im      = (const float*)d_in[5];
    const float* C_re      = (const float*)d_in[6];
    const float* C_im      = (const float*)d_in[7];
    const float* D_param   = (const float*)d_in[8];
    const float* gamma_log = (const float*)d_in[9];

    char* ws = (char*)d_ws;
    size_t off = 0;
    ushort* Xb   = (ushort*)(ws + off); off += (size_t)MROWS * 512 * 2;
    ushort* BT   = (ushort*)(ws + off); off += (size_t)1024 * 512 * 2;
    ushort* CT   = (ushort*)(ws + off); off += (size_t)512 * 1024 * 2;
    ushort* BuRe = (ushort*)(ws + off); off += (size_t)MROWS * 512 * 2;
    ushort* BuIm = (ushort*)(ws + off); off += (size_t)MROWS * 512 * 2;
    ushort* Hbf  = (ushort*)(ws + off); off += (size_t)MROWS * 1024 * 2;
    float*  cRe  = (float*)(ws + off); off += (size_t)NBATCH * NCHUNK * 512 * 4;
    float*  cIm  = (float*)(ws + off); off += (size_t)NBATCH * NCHUNK * 512 * 4;

    float* y_out = (float*)d_out;
    float* newH  = (float*)d_out + (size_t)MROWS * 512;

    const int tail = out_size - MROWS * 512;
    int newh_mode = 0;
    if (tail == NBATCH * 512 * 2) newh_mode = 1;       // planar [re|im] (validated)
    else if (tail == NBATCH * 512) newh_mode = 2;

    // prep: x->bf16 + coalesced B/C transposes
    k_prep<<<dim3(XBLK + TBLK), dim3(256), 0, stream>>>(
        x, B_re, B_im, gamma_log, C_re, C_im, Xb, BT, CT);

    // GEMM1: Bu(bf16 planes) = Xb (32768x512) * BT^T (1024x512); 2048 blocks
    k_gemm<512, 1, 8><<<dim3(2048), dim3(256), 0, stream>>>(
        Xb, BT, BuRe, BuIm, nullptr, nullptr, nullptr);

    // scan: local carries, then fused prefix+phase3
    k_scan1<<<dim3(NBATCH * NCHUNK), dim3(256), 0, stream>>>(BuRe, BuIm, nu_log, theta_log, cRe, cIm);
    k_scanB<<<dim3(NBATCH * NCHUNK), dim3(256), 0, stream>>>(
        BuRe, BuIm, cRe, cIm, h0, nu_log, theta_log, Hbf, newH, newh_mode);

    // GEMM2: y = Hbf (32768x1024) * CT^T (512x1024) + D*x; 1024 blocks
    k_gemm<1024, 2, 4><<<dim3(1024), dim3(256), 0, stream>>>(
        Hbf, CT, nullptr, nullptr, y_out, x, D_param);
}

// Round 9
// 289.943 us; speedup vs baseline: 1.2021x; 1.2021x over previous
//
#include <hip/hip_runtime.h>

// Problem constants
#define T_LEN 4096
#define DMODEL 512
#define DIM 512
#define NBATCH 8
#define MROWS (NBATCH * T_LEN)   // 32768
#define NCHUNK 128
#define LCHUNK 32                 // T_LEN / NCHUNK

typedef __attribute__((ext_vector_type(8))) short short8;
typedef __attribute__((ext_vector_type(4))) float float4v;

__device__ __forceinline__ ushort f2b(float f) {
    union { float fl; unsigned u; } v; v.fl = f;
    unsigned u = v.u;
    return (ushort)((u + 0x7FFFu + ((u >> 16) & 1u)) >> 16);
}
__device__ __forceinline__ float b2f(ushort u) {
    union { unsigned u; float f; } v; v.u = (unsigned)u << 16; return v.f;
}

__device__ __forceinline__ void glds16(const ushort* g, ushort* l) {
    __builtin_amdgcn_global_load_lds(
        (const __attribute__((address_space(1))) void*)g,
        (__attribute__((address_space(3))) void*)l, 16, 0, 0);
}

// ---------------- merged prep kernel (R6, verified) ----------------
#define XBLK (MROWS * 512 / 4 / 256)        // 16384
#define TBLK 256                            // 4 mats x 64 tiles of 64x64

__global__ __launch_bounds__(256) void k_prep(const float* __restrict__ x,
                                              const float* __restrict__ B_re,
                                              const float* __restrict__ B_im,
                                              const float* __restrict__ gamma_log,
                                              const float* __restrict__ C_re,
                                              const float* __restrict__ C_im,
                                              ushort* __restrict__ Xb,
                                              ushort* __restrict__ BT,
                                              ushort* __restrict__ CT) {
    __shared__ float T[64][65];
    int bb = blockIdx.x;
    if (bb < XBLK) {
        int i = (bb * 256 + threadIdx.x) * 4;
        float4 v = *(const float4*)(x + i);
        ushort4 o;
        o.x = f2b(v.x); o.y = f2b(v.y); o.z = f2b(v.z); o.w = f2b(v.w);
        *(ushort4*)(Xb + i) = o;
        return;
    }
    int tb = bb - XBLK;                 // 0..255
    int mat = tb >> 6;                  // 0=B_re 1=B_im 2=C_re 3=C_im
    int tile = tb & 63;
    int r0 = (tile >> 3) * 64;
    int c0 = (tile & 7) * 64;
    const float* IN = (mat == 0) ? B_re : (mat == 1) ? B_im : (mat == 2) ? C_re : C_im;
    int lr_ = threadIdx.x & 63;
    int lc  = threadIdx.x >> 6;
#pragma unroll
    for (int p = 0; p < 16; p++)
        T[4 * p + lc][lr_] = IN[(size_t)(c0 + 4 * p + lc) * 512 + r0 + lr_];
    __syncthreads();
#pragma unroll
    for (int p = 0; p < 16; p++) {
        int rr = 4 * p + lc;
        int r = r0 + rr;
        float v = T[lr_][rr];
        if (mat <= 1) {
            v *= __expf(gamma_log[r]);
            BT[(size_t)(mat * 512 + r) * 512 + c0 + lr_] = f2b(v);
        } else {
            if (mat == 3) v = -v;
            CT[(size_t)r * 1024 + (mat - 2) * 512 + c0 + lr_] = f2b(v);
        }
    }
}

// ---------------- bf16 MFMA GEMM: R1 tile/schedule, 8 waves per block ----------------
// R9 single-variable test: same 128x128 tile, BK=64, glds16 + XOR-swizzle (0 conflicts,
// verified), same 2-barrier loop — but 512 thr = 8 waves (2m x 4n), each owning 64x32.
// acc halves (32 VGPR) -> ~6 waves/SIMD; 2x resident waves/CU so one block's vmcnt
// drain overlaps another's MFMA (m114). Occupancy was pinned at 17% in ALL prior
// configs — this attacks the wave count, not the schedule.
template<int K, int MODE, int NBN>
__global__ __launch_bounds__(512) void k_gemm(
    const ushort* __restrict__ A, const ushort* __restrict__ Bt,
    ushort* __restrict__ oRe, ushort* __restrict__ oIm,
    float* __restrict__ y, const float* __restrict__ x, const float* __restrict__ Dp) {
    __shared__ ushort sA[128 * 64];
    __shared__ ushort sB[128 * 64];
    const int tid = threadIdx.x;
    // XCD-aware remap: round-robin block->XCD (L%8); XCD owns 32 m-blocks, n fastest.
    const int L = blockIdx.x;
    const int xcd = L & 7;
    const int slot = L >> 3;
    const int m0 = (xcd * 32 + slot / NBN) * 128;
    const int n0 = (slot % NBN) * 128;
    const int wave = tid >> 6;              // 0..7
    const int lane = tid & 63;
    const int wm = (wave >> 2) * 64;        // 0,64
    const int wn = (wave & 3) * 32;         // 0,32,64,96
    const int lr = lane & 15;
    const int quad = lane >> 4;

    // staging: wave w covers rows [w*16, w*16+16), 2 calls x 8 rows per matrix.
    const int srow = lane >> 3;                 // 0..7 within 8-row group
    const int schunk = (lane & 7) ^ srow;       // XOR swizzle key = row&7 = srow
    const ushort* gA0 = A + (size_t)(m0 + wave * 16 + srow) * K + schunk * 8;
    const ushort* gB0 = Bt + (size_t)(n0 + wave * 16 + srow) * K + schunk * 8;

    float4v acc[4][2];
#pragma unroll
    for (int i = 0; i < 4; i++)
#pragma unroll
        for (int j = 0; j < 2; j++) {
            float4v z = {0.f, 0.f, 0.f, 0.f};
            acc[i][j] = z;
        }

    for (int k0 = 0; k0 < K; k0 += 64) {
        __syncthreads();
#pragma unroll
        for (int c = 0; c < 2; c++) {
            glds16(gA0 + (size_t)(c * 8) * K + k0, &sA[(wave * 16 + c * 8) * 64]);
            glds16(gB0 + (size_t)(c * 8) * K + k0, &sB[(wave * 16 + c * 8) * 64]);
        }
        __syncthreads();

#pragma unroll
        for (int kk = 0; kk < 2; kk++) {
            short8 af[4], bfr[2];
#pragma unroll
            for (int i = 0; i < 4; i++) {
                int row = wm + i * 16 + lr;
                af[i] = *(const short8*)&sA[row * 64 + (((kk * 4 + quad) ^ (row & 7)) * 8)];
            }
#pragma unroll
            for (int j = 0; j < 2; j++) {
                int row = wn + j * 16 + lr;
                bfr[j] = *(const short8*)&sB[row * 64 + (((kk * 4 + quad) ^ (row & 7)) * 8)];
            }
#pragma unroll
            for (int i = 0; i < 4; i++)
#pragma unroll
                for (int j = 0; j < 2; j++)
                    acc[i][j] = __builtin_amdgcn_mfma_f32_16x16x32_bf16(af[i], bfr[j], acc[i][j], 0, 0, 0);
        }
    }

    // epilogue: D[row][col], col = lane&15, row = quad*4 + r
#pragma unroll
    for (int i = 0; i < 4; i++) {
#pragma unroll
        for (int j = 0; j < 2; j++) {
            int gmb = m0 + wm + i * 16 + quad * 4;
            int gn = n0 + wn + j * 16 + lr;
#pragma unroll
            for (int r = 0; r < 4; r++) {
                float v = acc[i][j][r];
                int row = gmb + r;
                if (MODE == 1) {
                    if (gn < 512) oRe[(size_t)row * 512 + gn] = f2b(v);
                    else oIm[(size_t)row * 512 + (gn - 512)] = f2b(v);
                } else {
                    size_t o = (size_t)row * 512 + gn;
                    y[o] = v + Dp[gn] * x[o];
                }
            }
        }
    }
}

// ---------------- scan kernels (R6, verified) ----------------

__device__ __forceinline__ void lambda_of(const float* nu_log, const float* theta_log,
                                          int n, float& lre, float& lim) {
    float e = __expf(nu_log[n]);
    float th = __expf(theta_log[n]);
    float rad = __expf(-e);
    float s, c;
    __sincosf(th, &s, &c);
    lre = rad * c;
    lim = rad * s;
}

__global__ __launch_bounds__(256) void k_scan1(const ushort* __restrict__ BuRe,
                                               const ushort* __restrict__ BuIm,
                                               const float* __restrict__ nu_log,
                                               const float* __restrict__ theta_log,
                                               float* __restrict__ cRe, float* __restrict__ cIm) {
    int n2 = threadIdx.x;
    int b = blockIdx.x >> 7;
    int c = blockIdx.x & 127;
    float lre0, lim0, lre1, lim1;
    lambda_of(nu_log, theta_log, 2 * n2, lre0, lim0);
    lambda_of(nu_log, theta_log, 2 * n2 + 1, lre1, lim1);
    float hr0 = 0.f, hi0 = 0.f, hr1 = 0.f, hi1 = 0.f;
    size_t base = ((size_t)b * T_LEN + (size_t)c * LCHUNK) * 512 + 2 * n2;
#pragma unroll 8
    for (int j = 0; j < LCHUNK; j++) {
        ushort2 ur = *(const ushort2*)(BuRe + base + (size_t)j * 512);
        ushort2 ui = *(const ushort2*)(BuIm + base + (size_t)j * 512);
        float br0 = b2f(ur.x), br1 = b2f(ur.y), bi0 = b2f(ui.x), bi1 = b2f(ui.y);
        float nr0 = lre0 * hr0 - lim0 * hi0 + br0;
        float ni0 = lre0 * hi0 + lim0 * hr0 + bi0;
        hr0 = nr0; hi0 = ni0;
        float nr1 = lre1 * hr1 - lim1 * hi1 + br1;
        float ni1 = lre1 * hi1 + lim1 * hr1 + bi1;
        hr1 = nr1; hi1 = ni1;
    }
    size_t co = ((size_t)b * NCHUNK + c) * 512 + 2 * n2;
    *(float2*)(cRe + co) = make_float2(hr0, hr1);
    *(float2*)(cIm + co) = make_float2(hi0, hi1);
}

__global__ __launch_bounds__(256) void k_scanB(const ushort* __restrict__ BuRe,
                                               const ushort* __restrict__ BuIm,
                                               const float* __restrict__ cRe,
                                               const float* __restrict__ cIm,
                                               const float* __restrict__ h0,
                                               const float* __restrict__ nu_log,
                                               const float* __restrict__ theta_log,
                                               ushort* __restrict__ Hbf,
                                               float* __restrict__ newH, int newh_mode) {
    int n2 = threadIdx.x;
    int b = blockIdx.x >> 7;
    int c = blockIdx.x & 127;
    float lre0, lim0, lre1, lim1;
    lambda_of(nu_log, theta_log, 2 * n2, lre0, lim0);
    lambda_of(nu_log, theta_log, 2 * n2 + 1, lre1, lim1);
    float Lr0 = lre0, Li0 = lim0, Lr1 = lre1, Li1 = lim1;
#pragma unroll
    for (int s = 0; s < 5; s++) {
        float a0 = Lr0 * Lr0 - Li0 * Li0, q0 = 2.f * Lr0 * Li0; Lr0 = a0; Li0 = q0;
        float a1 = Lr1 * Lr1 - Li1 * Li1, q1 = 2.f * Lr1 * Li1; Lr1 = a1; Li1 = q1;
    }
    float fr0 = h0[b * 512 + 2 * n2], fi0 = 0.f;
    float fr1 = h0[b * 512 + 2 * n2 + 1], fi1 = 0.f;
    size_t cb = (size_t)b * NCHUNK * 512 + 2 * n2;
#pragma unroll 4
    for (int j = 0; j < c; j++) {
        float2 ar = *(const float2*)(cRe + cb + (size_t)j * 512);
        float2 ai = *(const float2*)(cIm + cb + (size_t)j * 512);
        float nr0 = Lr0 * fr0 - Li0 * fi0 + ar.x;
        float ni0 = Lr0 * fi0 + Li0 * fr0 + ai.x;
        fr0 = nr0; fi0 = ni0;
        float nr1 = Lr1 * fr1 - Li1 * fi1 + ar.y;
        float ni1 = Lr1 * fi1 + Li1 * fr1 + ai.y;
        fr1 = nr1; fi1 = ni1;
    }
    if (c == NCHUNK - 1) {
        float2 ar = *(const float2*)(cRe + cb + (size_t)(NCHUNK - 1) * 512);
        float2 ai = *(const float2*)(cIm + cb + (size_t)(NCHUNK - 1) * 512);
        float cr0 = Lr0 * fr0 - Li0 * fi0 + ar.x;
        float ci0 = Lr0 * fi0 + Li0 * fr0 + ai.x;
        float cr1 = Lr1 * fr1 - Li1 * fi1 + ar.y;
        float ci1 = Lr1 * fi1 + Li1 * fr1 + ai.y;
        size_t i0 = (size_t)b * 512 + 2 * n2;
        if (newh_mode == 1) {
            newH[i0] = cr0; newH[i0 + 1] = cr1;
            newH[(size_t)NBATCH * 512 + i0] = ci0;
            newH[(size_t)NBATCH * 512 + i0 + 1] = ci1;
        } else if (newh_mode == 2) {
            newH[i0] = cr0; newH[i0 + 1] = cr1;
        } else {
            newH[i0 * 2] = cr0; newH[i0 * 2 + 1] = ci0;
            newH[(i0 + 1) * 2] = cr1; newH[(i0 + 1) * 2 + 1] = ci1;
        }
    }
    float pr0 = lre0, pi0 = lim0, pr1 = lre1, pi1 = lim1;
    float hr0 = 0.f, hi0 = 0.f, hr1 = 0.f, hi1 = 0.f;
    size_t row0 = (size_t)b * T_LEN + (size_t)c * LCHUNK;
#pragma unroll 4
    for (int j = 0; j < LCHUNK; j++) {
        size_t base = (row0 + j) * 512 + 2 * n2;
        ushort2 ur = *(const ushort2*)(BuRe + base);
        ushort2 ui = *(const ushort2*)(BuIm + base);
        float br0 = b2f(ur.x), br1 = b2f(ur.y), bi0 = b2f(ui.x), bi1 = b2f(ui.y);
        float nr0 = lre0 * hr0 - lim0 * hi0 + br0;
        float ni0 = lre0 * hi0 + lim0 * hr0 + bi0;
        hr0 = nr0; hi0 = ni0;
        float nr1 = lre1 * hr1 - lim1 * hi1 + br1;
        float ni1 = lre1 * hi1 + lim1 * hr1 + bi1;
        hr1 = nr1; hi1 = ni1;
        float vr0 = hr0 + pr0 * fr0 - pi0 * fi0;
        float vi0 = hi0 + pr0 * fi0 + pi0 * fr0;
        float vr1 = hr1 + pr1 * fr1 - pi1 * fi1;
        float vi1 = hi1 + pr1 * fi1 + pi1 * fr1;
        size_t hrow = (row0 + j) * 1024;
        ushort2 wre, wim;
        wre.x = f2b(vr0); wre.y = f2b(vr1);
        wim.x = f2b(vi0); wim.y = f2b(vi1);
        *(ushort2*)(Hbf + hrow + 2 * n2) = wre;
        *(ushort2*)(Hbf + hrow + 512 + 2 * n2) = wim;
        float npr0 = pr0 * lre0 - pi0 * lim0;
        float npi0 = pr0 * lim0 + pi0 * lre0;
        pr0 = npr0; pi0 = npi0;
        float npr1 = pr1 * lre1 - pi1 * lim1;
        float npi1 = pr1 * lim1 + pi1 * lre1;
        pr1 = npr1; pi1 = npi1;
    }
}

// ---------------- launch ----------------

extern "C" void kernel_launch(void* const* d_in, const int* in_sizes, int n_in,
                              void* d_out, int out_size, void* d_ws, size_t ws_size,
                              hipStream_t stream) {
    const float* x         = (const float*)d_in[0];
    const float* h0        = (const float*)d_in[1];
    const float* nu_log    = (const float*)d_in[2];
    const float* theta_log = (const float*)d_in[3];
    const float* B_re      = (const float*)d_in[4];
    const float* B_im      = (const float*)d_in[5];
    const float* C_re      = (const float*)d_in[6];
    const float* C_im      = (const float*)d_in[7];
    const float* D_param   = (const float*)d_in[8];
    const float* gamma_log = (const float*)d_in[9];

    char* ws = (char*)d_ws;
    size_t off = 0;
    ushort* Xb   = (ushort*)(ws + off); off += (size_t)MROWS * 512 * 2;
    ushort* BT   = (ushort*)(ws + off); off += (size_t)1024 * 512 * 2;
    ushort* CT   = (ushort*)(ws + off); off += (size_t)512 * 1024 * 2;
    ushort* BuRe = (ushort*)(ws + off); off += (size_t)MROWS * 512 * 2;
    ushort* BuIm = (ushort*)(ws + off); off += (size_t)MROWS * 512 * 2;
    ushort* Hbf  = (ushort*)(ws + off); off += (size_t)MROWS * 1024 * 2;
    float*  cRe  = (float*)(ws + off); off += (size_t)NBATCH * NCHUNK * 512 * 4;
    float*  cIm  = (float*)(ws + off); off += (size_t)NBATCH * NCHUNK * 512 * 4;

    float* y_out = (float*)d_out;
    float* newH  = (float*)d_out + (size_t)MROWS * 512;

    const int tail = out_size - MROWS * 512;
    int newh_mode = 0;
    if (tail == NBATCH * 512 * 2) newh_mode = 1;       // planar [re|im] (validated)
    else if (tail == NBATCH * 512) newh_mode = 2;

    // prep: x->bf16 + coalesced B/C transposes
    k_prep<<<dim3(XBLK + TBLK), dim3(256), 0, stream>>>(
        x, B_re, B_im, gamma_log, C_re, C_im, Xb, BT, CT);

    // GEMM1: Bu(bf16 planes) = Xb (32768x512) * BT^T (1024x512); 2048 blocks x 8 waves
    k_gemm<512, 1, 8><<<dim3(2048), dim3(512), 0, stream>>>(
        Xb, BT, BuRe, BuIm, nullptr, nullptr, nullptr);

    // scan: local carries, then fused prefix+phase3
    k_scan1<<<dim3(NBATCH * NCHUNK), dim3(256), 0, stream>>>(BuRe, BuIm, nu_log, theta_log, cRe, cIm);
    k_scanB<<<dim3(NBATCH * NCHUNK), dim3(256), 0, stream>>>(
        BuRe, BuIm, cRe, cIm, h0, nu_log, theta_log, Hbf, newH, newh_mode);

    // GEMM2: y = Hbf (32768x1024) * CT^T (512x1024) + D*x; 1024 blocks x 8 waves
    k_gemm<1024, 2, 4><<<dim3(1024), dim3(512), 0, stream>>>(
        Hbf, CT, nullptr, nullptr, y_out, x, D_param);
}